// Round 4
// baseline (157.817 us; speedup 1.0000x reference)
//
#include <hip/hip_runtime.h>

// QuantumLayer: 4-qubit, 4-layer VQC over batch B.
// R10 = R9 scalar structure, register-budget poison removed:
//  - NO __launch_bounds__. R8 (256,6)->VGPR 40 and R9 (256,4)->VGPR 64 both
//    came in BELOW the nominal cap and demoted the state to scratch
//    (~400 MB/dispatch of spill traffic, kernel 105-115us). The v2f builds
//    with identical array structure at (256,3)/(256,4) were clean, so the
//    bound -- not the arrays -- is the poison. Default budget (256) lets the
//    allocator take the ~70-100 VGPRs the scalar stream actually needs.
//  - __sinf/__cosf instead of __sincosf(&s,&c): no address-taken locals
//    (defensive vs stack demotion; AMD has no fused sincos HW op anyway).
//  Theory retained: scalar v_fma_f32 is 2 cyc/wave64 (measured m07) vs
//  v_pk_fma_f32 at effective half FLOP rate; same per-element op count
//  -> kernel should drop from ~32us toward the ~13us issue floor.
//  Kept: fused precompute (M = RZ*RY in LDS), layer-3 RZ dropped (exact),
//  full unroll (CNOTs = register renames), folded butterfly measurement.
// State indexing: flat k = w0*8 + w1*4 + w2*2 + w3  (wire i -> bit (3-i)).

// G = M * RX(c, s) is SU(2): G = [[g, d], [-conj(d), conj(g)]].
// Msh quad = {ar, ai, br, bi} (M = [[a, b], [-conj(b), conj(a)]]).
__device__ __forceinline__ void make_g2(const float4* Msh, int idx,
                                        float c, float s,
                                        float& gr, float& gi, float& dr, float& di) {
  float4 m = Msh[idx];  // ds_read_b128, wave-uniform broadcast
  gr = m.x * c + m.w * s;
  gi = m.y * c - m.z * s;
  dr = m.y * s + m.z * c;
  di = m.w * c - m.x * s;
}

// Layer-3 variant: RZ == I there, so M = RY is REAL (ai = bi = 0).
__device__ __forceinline__ void make_g2_real(const float4* Msh, int idx,
                                             float c, float s,
                                             float& gr, float& gi, float& dr, float& di) {
  float4 m = Msh[idx];
  gr = m.x * c;
  gi = -(m.z * s);
  dr = m.z * c;
  di = -(m.x * s);
}

// Apply SU(2) gate [[g,d],[-conj(d),conj(g)]] on wire W (bit 3-W).
template <int W>
__device__ __forceinline__ void apply_su2(float (&sr)[16], float (&si)[16],
                                          float gr, float gi, float dr, float di) {
  constexpr int stride = 8 >> W;
#pragma unroll
  for (int base = 0; base < 16; base += 2 * stride) {
#pragma unroll
    for (int j = 0; j < stride; ++j) {
      const int k0 = base + j, k1 = k0 + stride;
      float a0r = sr[k0], a0i = si[k0], a1r = sr[k1], a1i = si[k1];
      sr[k0] = gr * a0r - gi * a0i + dr * a1r - di * a1i;
      si[k0] = gr * a0i + gi * a0r + dr * a1i + di * a1r;
      sr[k1] = gr * a1r + gi * a1i - dr * a0r - di * a0i;
      si[k1] = gr * a1i - gi * a1r - dr * a0i + di * a0r;
    }
  }
}

// CNOT(control C, target T): pure register permutation (fully unrolled).
template <int C, int T>
__device__ __forceinline__ void apply_cnot_(float (&sr)[16], float (&si)[16]) {
  constexpr int cb = 8 >> C, tb = 8 >> T;
#pragma unroll
  for (int k = 0; k < 16; ++k) {
    if ((k & cb) && !(k & tb)) {
      const int k2 = k | tb;
      float tr = sr[k]; sr[k] = sr[k2]; sr[k2] = tr;
      float ti = si[k]; si[k] = si[k2]; si[k2] = ti;
    }
  }
}

__global__ void qlayer_main(const float* __restrict__ x,
                            const float* __restrict__ w,
                            float* __restrict__ out) {
  // ---- Fused precompute: M = RZ(pz)*RY(py) per (layer, wire); layer 3 uses
  // RZ = I (exact: diagonal phase before the final CNOT block is
  // probability-invariant). float4 quads {ar,ai,br,bi} in LDS (256 B). ----
  __shared__ float4 Msh[16];
  int tid = threadIdx.x;
  if (tid < 16) {
    int l = tid >> 2, q = tid & 3;
    float ay = 0.5f * w[8 * l + q];                       // RY angle /2
    float az = (l == 3) ? 0.0f : 0.5f * w[8 * l + 4 + q]; // RZ angle /2 (I on l=3)
    float cy = __cosf(ay), sy = __sinf(ay);
    float cz = __cosf(az), sz = __sinf(az);
    Msh[tid] = make_float4(cz * cy, -sz * cy, -cz * sy, sz * sy);
  }

  int t = blockIdx.x * blockDim.x + tid;  // owns batch element t
  float4 xv = reinterpret_cast<const float4*>(x)[t];
  float cx[4], sx[4];
  cx[0] = __cosf(0.5f * xv.x); sx[0] = __sinf(0.5f * xv.x);
  cx[1] = __cosf(0.5f * xv.y); sx[1] = __sinf(0.5f * xv.y);
  cx[2] = __cosf(0.5f * xv.z); sx[2] = __sinf(0.5f * xv.z);
  cx[3] = __cosf(0.5f * xv.w); sx[3] = __sinf(0.5f * xv.w);

  __syncthreads();  // Msh ready

  float sr[16], si[16];

  // ---- Layer 0 on |0000>: product state, built IN-PLACE LSB-first.
  // bit=0 branch * g; bit=1 branch * -conj(d) = (-dr,+di):
  //   re = -dr*ar - di*ai,   im = di*ar - dr*ai. ----
  {
    float gr, gi, dr, di;
    make_g2(Msh, 3, cx[3], sx[3], gr, gi, dr, di);
    sr[0] = gr;  si[0] = gi;
    sr[1] = -dr; si[1] = di;
    make_g2(Msh, 2, cx[2], sx[2], gr, gi, dr, di);
#pragma unroll
    for (int k = 1; k >= 0; --k) {
      float ar_ = sr[k], ai_ = si[k];
      sr[k + 2] = -(dr * ar_) - di * ai_;
      si[k + 2] = di * ar_ - dr * ai_;
      sr[k]     = gr * ar_ - gi * ai_;
      si[k]     = gr * ai_ + gi * ar_;
    }
    make_g2(Msh, 1, cx[1], sx[1], gr, gi, dr, di);
#pragma unroll
    for (int k = 3; k >= 0; --k) {
      float ar_ = sr[k], ai_ = si[k];
      sr[k + 4] = -(dr * ar_) - di * ai_;
      si[k + 4] = di * ar_ - dr * ai_;
      sr[k]     = gr * ar_ - gi * ai_;
      si[k]     = gr * ai_ + gi * ar_;
    }
    make_g2(Msh, 0, cx[0], sx[0], gr, gi, dr, di);
#pragma unroll
    for (int k = 7; k >= 0; --k) {
      float ar_ = sr[k], ai_ = si[k];
      sr[k + 8] = -(dr * ar_) - di * ai_;
      si[k + 8] = di * ar_ - dr * ai_;
      sr[k]     = gr * ar_ - gi * ai_;
      si[k]     = gr * ai_ + gi * ar_;
    }
  }
  apply_cnot_<2, 3>(sr, si);
  apply_cnot_<1, 2>(sr, si);
  apply_cnot_<0, 1>(sr, si);
  apply_cnot_<3, 0>(sr, si);

  // ---- Layers 1..2 (fully unrolled: CNOTs stay register renames) ----
#pragma unroll
  for (int l = 1; l < 3; ++l) {
    float gr, gi, dr, di;
    make_g2(Msh, l * 4 + 0, cx[0], sx[0], gr, gi, dr, di);
    apply_su2<0>(sr, si, gr, gi, dr, di);
    make_g2(Msh, l * 4 + 1, cx[1], sx[1], gr, gi, dr, di);
    apply_su2<1>(sr, si, gr, gi, dr, di);
    make_g2(Msh, l * 4 + 2, cx[2], sx[2], gr, gi, dr, di);
    apply_su2<2>(sr, si, gr, gi, dr, di);
    make_g2(Msh, l * 4 + 3, cx[3], sx[3], gr, gi, dr, di);
    apply_su2<3>(sr, si, gr, gi, dr, di);
    apply_cnot_<2, 3>(sr, si);
    apply_cnot_<1, 2>(sr, si);
    apply_cnot_<0, 1>(sr, si);
    apply_cnot_<3, 0>(sr, si);
  }

  // ---- Layer 3: M real (RZ folded out) ----
  {
    float gr, gi, dr, di;
    make_g2_real(Msh, 12, cx[0], sx[0], gr, gi, dr, di);
    apply_su2<0>(sr, si, gr, gi, dr, di);
    make_g2_real(Msh, 13, cx[1], sx[1], gr, gi, dr, di);
    apply_su2<1>(sr, si, gr, gi, dr, di);
    make_g2_real(Msh, 14, cx[2], sx[2], gr, gi, dr, di);
    apply_su2<2>(sr, si, gr, gi, dr, di);
    make_g2_real(Msh, 15, cx[3], sx[3], gr, gi, dr, di);
    apply_su2<3>(sr, si, gr, gi, dr, di);
    apply_cnot_<2, 3>(sr, si);
    apply_cnot_<1, 2>(sr, si);
    apply_cnot_<0, 1>(sr, si);
    apply_cnot_<3, 0>(sr, si);
  }

  // ---- Measurement: fold |amp|^2 into the first butterfly level so state
  // regs die as consumed. o_i = sum_k p_k * (bit(3-i)?-1:+1). ----
  float s2[8], d2[8];
#pragma unroll
  for (int k = 0; k < 8; ++k) {
    float p0 = sr[2 * k]     * sr[2 * k]     + si[2 * k]     * si[2 * k];
    float p1 = sr[2 * k + 1] * sr[2 * k + 1] + si[2 * k + 1] * si[2 * k + 1];
    s2[k] = p0 + p1;
    d2[k] = p0 - p1;
  }
  float o3 = ((d2[0] + d2[1]) + (d2[2] + d2[3])) + ((d2[4] + d2[5]) + (d2[6] + d2[7]));
  float s4[4], d4[4];
#pragma unroll
  for (int k = 0; k < 4; ++k) {
    s4[k] = s2[2 * k] + s2[2 * k + 1];
    d4[k] = s2[2 * k] - s2[2 * k + 1];
  }
  float o2 = (d4[0] + d4[1]) + (d4[2] + d4[3]);
  float s8a = s4[0] + s4[1], s8b = s4[2] + s4[3];
  float d8a = s4[0] - s4[1], d8b = s4[2] - s4[3];
  float o1 = d8a + d8b;
  float o0 = s8a - s8b;

  reinterpret_cast<float4*>(out)[t] = make_float4(o0, o1, o2, o3);
}

extern "C" void kernel_launch(void* const* d_in, const int* in_sizes, int n_in,
                              void* d_out, int out_size, void* d_ws, size_t ws_size,
                              hipStream_t stream) {
  const float* x = (const float*)d_in[0];
  const float* w = (const float*)d_in[1];
  float* out = (float*)d_out;
  int nb = in_sizes[0] / 4;  // batch elements; B=524288

  int blocks = nb / 256;     // exact: 2048 blocks, 1 element/thread
  hipLaunchKernelGGL(qlayer_main, dim3(blocks), dim3(256), 0, stream, x, w, out);
}

// Round 6
// 90.286 us; speedup vs baseline: 1.7480x; 1.7480x over previous
//
#include <hip/hip_runtime.h>

// QuantumLayer: 4-qubit, 4-layer VQC over batch B.
// R12 = R11 resubmitted verbatim (R11 bench died on container acquisition,
// not on the kernel: no compile/pytest/absmax signal -> theory untested).
//
// R11: scalar stream with state as 32 NAMED SCALARS (r0..r15, i0..i15).
//  R8-R10 post-mortem: float sr[16]/si[16] arrays were demoted to scratch
//  by the compiler REGARDLESS of launch_bounds (VGPR_Count 40/64/64, ~400MB
//  spill traffic per dispatch, kernel 105-115us). SROA gives up on the
//  fully-unrolled ~2000-inst body; named scalars enter SSA directly and
//  cannot be aggregate-demoted. Token-pasting macros express the gate
//  pair structure; CNOTs remain pure SSA renames.
//  __launch_bounds__(256) single-arg: declares 4-wave blocks without the
//  2nd-arg VGPR strangle.
//  Theory retained: ~1900 v_fma_f32 @ 2cyc/wave64, 8 waves/SIMD -> ~13us
//  issue floor vs v2f's ~32us half-rate-pk stream.
//  Kept: fused precompute (M = RZ*RY in LDS), layer-3 RZ dropped (exact),
//  full unroll, folded butterfly measurement.
// State indexing: flat k = w0*8 + w1*4 + w2*2 + w3  (wire i -> bit (3-i)).

// --- gate application on a named pair (k0: target bit 0, k1: target bit 1)
#define GATE_APPLY(K0, K1) do {                                         \
    float a0r = r##K0, a0i = i##K0, a1r = r##K1, a1i = i##K1;           \
    r##K0 = gr * a0r - gi * a0i + dr * a1r - di * a1i;                  \
    i##K0 = gr * a0i + gi * a0r + dr * a1i + di * a1r;                  \
    r##K1 = gr * a1r + gi * a1i - dr * a0r - di * a0i;                  \
    i##K1 = gr * a1i - gi * a1r - dr * a0i + di * a0r;                  \
  } while (0)

// SU(2) on wire W = pair list with stride 8>>W (wire i -> bit (3-i)).
#define SU2_W0 do { GATE_APPLY(0,8); GATE_APPLY(1,9); GATE_APPLY(2,10); GATE_APPLY(3,11); \
                    GATE_APPLY(4,12); GATE_APPLY(5,13); GATE_APPLY(6,14); GATE_APPLY(7,15); } while (0)
#define SU2_W1 do { GATE_APPLY(0,4); GATE_APPLY(1,5); GATE_APPLY(2,6); GATE_APPLY(3,7);   \
                    GATE_APPLY(8,12); GATE_APPLY(9,13); GATE_APPLY(10,14); GATE_APPLY(11,15); } while (0)
#define SU2_W2 do { GATE_APPLY(0,2); GATE_APPLY(1,3); GATE_APPLY(4,6); GATE_APPLY(5,7);   \
                    GATE_APPLY(8,10); GATE_APPLY(9,11); GATE_APPLY(12,14); GATE_APPLY(13,15); } while (0)
#define SU2_W3 do { GATE_APPLY(0,1); GATE_APPLY(2,3); GATE_APPLY(4,5); GATE_APPLY(6,7);   \
                    GATE_APPLY(8,9); GATE_APPLY(10,11); GATE_APPLY(12,13); GATE_APPLY(14,15); } while (0)

// CNOT swaps (pure SSA renames).
#define SWAPK(A, B) do { float t_r = r##A; r##A = r##B; r##B = t_r;     \
                         float t_i = i##A; i##A = i##B; i##B = t_i; } while (0)
#define CNOT_23 do { SWAPK(2,3);  SWAPK(6,7);  SWAPK(10,11); SWAPK(14,15); } while (0)
#define CNOT_12 do { SWAPK(4,6);  SWAPK(5,7);  SWAPK(12,14); SWAPK(13,15); } while (0)
#define CNOT_01 do { SWAPK(8,12); SWAPK(9,13); SWAPK(10,14); SWAPK(11,15); } while (0)
#define CNOT_30 do { SWAPK(1,9);  SWAPK(3,11); SWAPK(5,13); SWAPK(7,15); } while (0)

// Layer-0 product-state expansion: K has new-bit=0 (times g),
// KP = K + stride has new-bit=1 (times -conj(d) = (-dr, +di)).
#define L0_EXPAND(K, KP) do {                                           \
    float e_ar = r##K, e_ai = i##K;                                     \
    r##KP = -(dr * e_ar) - di * e_ai;                                   \
    i##KP = di * e_ar - dr * e_ai;                                      \
    r##K  = gr * e_ar - gi * e_ai;                                      \
    i##K  = gr * e_ai + gi * e_ar;                                      \
  } while (0)

// G = M * RX(c, s) is SU(2): G = [[g, d], [-conj(d), conj(g)]].
// Msh quad = {ar, ai, br, bi} (M = [[a, b], [-conj(b), conj(a)]]).
__device__ __forceinline__ void make_g2(const float4* Msh, int idx,
                                        float c, float s,
                                        float& gr, float& gi, float& dr, float& di) {
  float4 m = Msh[idx];  // ds_read_b128, wave-uniform broadcast
  gr = m.x * c + m.w * s;
  gi = m.y * c - m.z * s;
  dr = m.y * s + m.z * c;
  di = m.w * c - m.x * s;
}

// Layer-3 variant: RZ == I there, so M = RY is REAL (ai = bi = 0).
__device__ __forceinline__ void make_g2_real(const float4* Msh, int idx,
                                             float c, float s,
                                             float& gr, float& gi, float& dr, float& di) {
  float4 m = Msh[idx];
  gr = m.x * c;
  gi = -(m.z * s);
  dr = m.z * c;
  di = -(m.x * s);
}

__global__ __launch_bounds__(256) void qlayer_main(const float* __restrict__ x,
                                                   const float* __restrict__ w,
                                                   float* __restrict__ out) {
  // ---- Fused precompute: M = RZ(pz)*RY(py) per (layer, wire); layer 3 uses
  // RZ = I (exact: diagonal phase before the final CNOT block is
  // probability-invariant). float4 quads {ar,ai,br,bi} in LDS (256 B). ----
  __shared__ float4 Msh[16];
  int tid = threadIdx.x;
  if (tid < 16) {
    int l = tid >> 2, q = tid & 3;
    float ay = 0.5f * w[8 * l + q];                       // RY angle /2
    float az = (l == 3) ? 0.0f : 0.5f * w[8 * l + 4 + q]; // RZ angle /2 (I on l=3)
    float cy = __cosf(ay), sy = __sinf(ay);
    float cz = __cosf(az), sz = __sinf(az);
    Msh[tid] = make_float4(cz * cy, -sz * cy, -cz * sy, sz * sy);
  }

  int t = blockIdx.x * blockDim.x + tid;  // owns batch element t
  float4 xv = reinterpret_cast<const float4*>(x)[t];
  float cx0 = __cosf(0.5f * xv.x), sx0 = __sinf(0.5f * xv.x);
  float cx1 = __cosf(0.5f * xv.y), sx1 = __sinf(0.5f * xv.y);
  float cx2 = __cosf(0.5f * xv.z), sx2 = __sinf(0.5f * xv.z);
  float cx3 = __cosf(0.5f * xv.w), sx3 = __sinf(0.5f * xv.w);

  __syncthreads();  // Msh ready

  // ---- State: 32 named scalars (cannot be aggregate-demoted to scratch) ----
  float r0, r1, r2, r3, r4, r5, r6, r7, r8, r9, r10, r11, r12, r13, r14, r15;
  float i0, i1, i2, i3, i4, i5, i6, i7, i8, i9, i10, i11, i12, i13, i14, i15;

  float gr, gi, dr, di;

  // ---- Layer 0 on |0000>: product state, built IN-PLACE LSB-first ----
  make_g2(Msh, 3, cx3, sx3, gr, gi, dr, di);
  r0 = gr;  i0 = gi;
  r1 = -dr; i1 = di;
  make_g2(Msh, 2, cx2, sx2, gr, gi, dr, di);
  L0_EXPAND(1, 3); L0_EXPAND(0, 2);
  make_g2(Msh, 1, cx1, sx1, gr, gi, dr, di);
  L0_EXPAND(3, 7); L0_EXPAND(2, 6); L0_EXPAND(1, 5); L0_EXPAND(0, 4);
  make_g2(Msh, 0, cx0, sx0, gr, gi, dr, di);
  L0_EXPAND(7, 15); L0_EXPAND(6, 14); L0_EXPAND(5, 13); L0_EXPAND(4, 12);
  L0_EXPAND(3, 11); L0_EXPAND(2, 10); L0_EXPAND(1, 9);  L0_EXPAND(0, 8);
  CNOT_23; CNOT_12; CNOT_01; CNOT_30;

  // ---- Layers 1..2 (full complex gates) ----
#pragma unroll
  for (int l = 1; l < 3; ++l) {
    make_g2(Msh, l * 4 + 0, cx0, sx0, gr, gi, dr, di); SU2_W0;
    make_g2(Msh, l * 4 + 1, cx1, sx1, gr, gi, dr, di); SU2_W1;
    make_g2(Msh, l * 4 + 2, cx2, sx2, gr, gi, dr, di); SU2_W2;
    make_g2(Msh, l * 4 + 3, cx3, sx3, gr, gi, dr, di); SU2_W3;
    CNOT_23; CNOT_12; CNOT_01; CNOT_30;
  }

  // ---- Layer 3: M real (RZ folded out, exact) ----
  make_g2_real(Msh, 12, cx0, sx0, gr, gi, dr, di); SU2_W0;
  make_g2_real(Msh, 13, cx1, sx1, gr, gi, dr, di); SU2_W1;
  make_g2_real(Msh, 14, cx2, sx2, gr, gi, dr, di); SU2_W2;
  make_g2_real(Msh, 15, cx3, sx3, gr, gi, dr, di); SU2_W3;
  CNOT_23; CNOT_12; CNOT_01; CNOT_30;

  // ---- Measurement: butterfly over p_k = r_k^2 + i_k^2;
  // o_j = sum_k p_k * (bit(3-j)? -1 : +1). ----
  float p0  = r0  * r0  + i0  * i0,  p1  = r1  * r1  + i1  * i1;
  float p2  = r2  * r2  + i2  * i2,  p3  = r3  * r3  + i3  * i3;
  float p4  = r4  * r4  + i4  * i4,  p5  = r5  * r5  + i5  * i5;
  float p6  = r6  * r6  + i6  * i6,  p7  = r7  * r7  + i7  * i7;
  float p8  = r8  * r8  + i8  * i8,  p9  = r9  * r9  + i9  * i9;
  float p10 = r10 * r10 + i10 * i10, p11 = r11 * r11 + i11 * i11;
  float p12 = r12 * r12 + i12 * i12, p13 = r13 * r13 + i13 * i13;
  float p14 = r14 * r14 + i14 * i14, p15 = r15 * r15 + i15 * i15;

  float s20 = p0 + p1,   d20 = p0 - p1;
  float s21 = p2 + p3,   d21 = p2 - p3;
  float s22 = p4 + p5,   d22 = p4 - p5;
  float s23 = p6 + p7,   d23 = p6 - p7;
  float s24 = p8 + p9,   d24 = p8 - p9;
  float s25 = p10 + p11, d25 = p10 - p11;
  float s26 = p12 + p13, d26 = p12 - p13;
  float s27 = p14 + p15, d27 = p14 - p15;
  float o3 = ((d20 + d21) + (d22 + d23)) + ((d24 + d25) + (d26 + d27));

  float s40 = s20 + s21, d40 = s20 - s21;
  float s41 = s22 + s23, d41 = s22 - s23;
  float s42 = s24 + s25, d42 = s24 - s25;
  float s43 = s26 + s27, d43 = s26 - s27;
  float o2 = (d40 + d41) + (d42 + d43);

  float s8a = s40 + s41, s8b = s42 + s43;
  float d8a = s40 - s41, d8b = s42 - s43;
  float o1 = d8a + d8b;
  float o0 = s8a - s8b;

  reinterpret_cast<float4*>(out)[t] = make_float4(o0, o1, o2, o3);
}

extern "C" void kernel_launch(void* const* d_in, const int* in_sizes, int n_in,
                              void* d_out, int out_size, void* d_ws, size_t ws_size,
                              hipStream_t stream) {
  const float* x = (const float*)d_in[0];
  const float* w = (const float*)d_in[1];
  float* out = (float*)d_out;
  int nb = in_sizes[0] / 4;  // batch elements; B=524288

  int blocks = nb / 256;     // exact: 2048 blocks, 1 element/thread
  hipLaunchKernelGGL(qlayer_main, dim3(blocks), dim3(256), 0, stream, x, w, out);
}

// Round 7
// 78.169 us; speedup vs baseline: 2.0189x; 1.1550x over previous
//
#include <hip/hip_runtime.h>

// QuantumLayer: 4-qubit, 4-layer VQC over batch B.
// R13: 4 elements/thread = TWO independent v2f streams (A, B), all state in
// NAMED v2f variables (R12 proved named vars dodge aggregate->scratch
// demotion; R8-R10's arrays all spilled).
//  Evidence so far: v2f (2 elem, R6) kernel ~32us beats clean scalar (R12)
//  ~46us -> v_pk_fma_f32 is FLOP-rate-equal to scalar (157.3 TF spec = the
//  scalar rate), and pk wins by halving instructions-to-schedule. R7: 3->4
//  waves null => not wave-starved; residual 32us vs ~13-25us floor is
//  dependency/stall time => attack with per-wave ILP: 2 streams/thread.
//  Kept: fused precompute (M=RZ*RY splatted v2f in LDS), layer-3 RZ dropped
//  (exact), full unroll (CNOTs = SSA renames), folded butterfly measurement.
// State indexing: flat k = w0*8 + w1*4 + w2*2 + w3  (wire i -> bit (3-i)).

typedef float v2f __attribute__((ext_vector_type(2)));

// ---- gate application on a named pair of one stream ----
#define GATE_APPLY(S, K0, K1) do {                                        \
    v2f a0r = sr##S##_##K0, a0i = si##S##_##K0;                           \
    v2f a1r = sr##S##_##K1, a1i = si##S##_##K1;                           \
    sr##S##_##K0 = gr##S * a0r - gi##S * a0i + dr##S * a1r - di##S * a1i; \
    si##S##_##K0 = gr##S * a0i + gi##S * a0r + dr##S * a1i + di##S * a1r; \
    sr##S##_##K1 = gr##S * a1r + gi##S * a1i - dr##S * a0r - di##S * a0i; \
    si##S##_##K1 = gr##S * a1i - gi##S * a1r - dr##S * a0i + di##S * a0r; \
  } while (0)

#define SU2_W0(S) do { GATE_APPLY(S,0,8);  GATE_APPLY(S,1,9);   GATE_APPLY(S,2,10);  GATE_APPLY(S,3,11); \
                       GATE_APPLY(S,4,12); GATE_APPLY(S,5,13);  GATE_APPLY(S,6,14);  GATE_APPLY(S,7,15); } while (0)
#define SU2_W1(S) do { GATE_APPLY(S,0,4);  GATE_APPLY(S,1,5);   GATE_APPLY(S,2,6);   GATE_APPLY(S,3,7);  \
                       GATE_APPLY(S,8,12); GATE_APPLY(S,9,13);  GATE_APPLY(S,10,14); GATE_APPLY(S,11,15); } while (0)
#define SU2_W2(S) do { GATE_APPLY(S,0,2);  GATE_APPLY(S,1,3);   GATE_APPLY(S,4,6);   GATE_APPLY(S,5,7);  \
                       GATE_APPLY(S,8,10); GATE_APPLY(S,9,11);  GATE_APPLY(S,12,14); GATE_APPLY(S,13,15); } while (0)
#define SU2_W3(S) do { GATE_APPLY(S,0,1);  GATE_APPLY(S,2,3);   GATE_APPLY(S,4,5);   GATE_APPLY(S,6,7);  \
                       GATE_APPLY(S,8,9);  GATE_APPLY(S,10,11); GATE_APPLY(S,12,13); GATE_APPLY(S,14,15); } while (0)

// CNOT block (2,3)(1,2)(0,1)(3,0): pure SSA renames.
#define SWAPK(S, A, B) do { v2f t_r = sr##S##_##A; sr##S##_##A = sr##S##_##B; sr##S##_##B = t_r; \
                            v2f t_i = si##S##_##A; si##S##_##A = si##S##_##B; si##S##_##B = t_i; } while (0)
#define CNOTS(S) do { SWAPK(S,2,3);  SWAPK(S,6,7);  SWAPK(S,10,11); SWAPK(S,14,15); \
                      SWAPK(S,4,6);  SWAPK(S,5,7);  SWAPK(S,12,14); SWAPK(S,13,15); \
                      SWAPK(S,8,12); SWAPK(S,9,13); SWAPK(S,10,14); SWAPK(S,11,15); \
                      SWAPK(S,1,9);  SWAPK(S,3,11); SWAPK(S,5,13); SWAPK(S,7,15); } while (0)

// Layer-0 product-state expansion: K keeps new-bit=0 (* g), KP gets
// new-bit=1 (* -conj(d) = (-dr, +di)).
#define L0_EXPAND(S, K, KP) do {                          \
    v2f e_ar = sr##S##_##K, e_ai = si##S##_##K;           \
    sr##S##_##KP = -(dr##S * e_ar) - di##S * e_ai;        \
    si##S##_##KP = di##S * e_ar - dr##S * e_ai;           \
    sr##S##_##K  = gr##S * e_ar - gi##S * e_ai;           \
    si##S##_##K  = gr##S * e_ai + gi##S * e_ar;           \
  } while (0)

// G = M * RX(c,s): one LDS load feeds BOTH streams' gate builds.
#define MAKE_G2_AB(IDX, Q) do {                                           \
    v2f m_ar = Msh[(IDX) * 4 + 0], m_ai = Msh[(IDX) * 4 + 1];             \
    v2f m_br = Msh[(IDX) * 4 + 2], m_bi = Msh[(IDX) * 4 + 3];             \
    grA = m_ar * cxA##Q + m_bi * sxA##Q;                                  \
    giA = m_ai * cxA##Q - m_br * sxA##Q;                                  \
    drA = m_ai * sxA##Q + m_br * cxA##Q;                                  \
    diA = m_bi * cxA##Q - m_ar * sxA##Q;                                  \
    grB = m_ar * cxB##Q + m_bi * sxB##Q;                                  \
    giB = m_ai * cxB##Q - m_br * sxB##Q;                                  \
    drB = m_ai * sxB##Q + m_br * cxB##Q;                                  \
    diB = m_bi * cxB##Q - m_ar * sxB##Q;                                  \
  } while (0)

// Layer-3 variant: RZ == I there, so M real (ai = bi = 0).
#define MAKE_G2_REAL_AB(IDX, Q) do {                                      \
    v2f m_ar = Msh[(IDX) * 4 + 0], m_br = Msh[(IDX) * 4 + 2];             \
    grA = m_ar * cxA##Q;  giA = -(m_br * sxA##Q);                         \
    drA = m_br * cxA##Q;  diA = -(m_ar * sxA##Q);                         \
    grB = m_ar * cxB##Q;  giB = -(m_br * sxB##Q);                         \
    drB = m_br * cxB##Q;  diB = -(m_ar * sxB##Q);                         \
  } while (0)

#define PSQ(S, K) (sr##S##_##K * sr##S##_##K + si##S##_##K * si##S##_##K)

// Butterfly measurement: o_j = sum_k p_k * (bit(3-j)? -1 : +1).
#define MEASURE(S) do {                                                   \
    v2f p0 = PSQ(S,0),  p1 = PSQ(S,1),  p2 = PSQ(S,2),  p3 = PSQ(S,3);    \
    v2f p4 = PSQ(S,4),  p5 = PSQ(S,5),  p6 = PSQ(S,6),  p7 = PSQ(S,7);    \
    v2f p8 = PSQ(S,8),  p9 = PSQ(S,9),  pa = PSQ(S,10), pb = PSQ(S,11);   \
    v2f pc = PSQ(S,12), pd = PSQ(S,13), pe = PSQ(S,14), pf = PSQ(S,15);   \
    v2f s20 = p0 + p1, d20 = p0 - p1,  s21 = p2 + p3, d21 = p2 - p3;      \
    v2f s22 = p4 + p5, d22 = p4 - p5,  s23 = p6 + p7, d23 = p6 - p7;      \
    v2f s24 = p8 + p9, d24 = p8 - p9,  s25 = pa + pb, d25 = pa - pb;      \
    v2f s26 = pc + pd, d26 = pc - pd,  s27 = pe + pf, d27 = pe - pf;      \
    o3##S = ((d20 + d21) + (d22 + d23)) + ((d24 + d25) + (d26 + d27));    \
    v2f s40 = s20 + s21, d40 = s20 - s21, s41 = s22 + s23, d41 = s22 - s23; \
    v2f s42 = s24 + s25, d42 = s24 - s25, s43 = s26 + s27, d43 = s26 - s27; \
    o2##S = (d40 + d41) + (d42 + d43);                                    \
    v2f s8a = s40 + s41, s8b = s42 + s43;                                 \
    v2f d8a = s40 - s41, d8b = s42 - s43;                                 \
    o1##S = d8a + d8b;                                                    \
    o0##S = s8a - s8b;                                                    \
  } while (0)

__global__ __launch_bounds__(256) void qlayer_main(const float* __restrict__ x,
                                                   const float* __restrict__ w,
                                                   float* __restrict__ out) {
  // ---- Fused precompute: M = RZ(pz)*RY(py) per (layer, wire); layer 3 uses
  // RZ = I (exact). Splatted v2f quads {ar,ai,br,bi} in LDS (512 B). ----
  __shared__ v2f Msh[16 * 4];
  int tid = threadIdx.x;
  if (tid < 16) {
    int l = tid >> 2, q = tid & 3;
    float ay = 0.5f * w[8 * l + q];
    float az = (l == 3) ? 0.0f : 0.5f * w[8 * l + 4 + q];
    float cy = __cosf(ay), sy = __sinf(ay);
    float cz = __cosf(az), sz = __sinf(az);
    float ar = cz * cy, ai = -sz * cy, br = -cz * sy, bi = sz * sy;
    Msh[tid * 4 + 0] = v2f{ar, ar};
    Msh[tid * 4 + 1] = v2f{ai, ai};
    Msh[tid * 4 + 2] = v2f{br, br};
    Msh[tid * 4 + 3] = v2f{bi, bi};
  }

  int t = blockIdx.x * blockDim.x + tid;  // owns batch elems 4t..4t+3
  const float4* x4 = reinterpret_cast<const float4*>(x);
  float4 xv0 = x4[4 * t + 0], xv1 = x4[4 * t + 1];
  float4 xv2 = x4[4 * t + 2], xv3 = x4[4 * t + 3];

  // Stream A = elems {4t, 4t+1}; stream B = {4t+2, 4t+3}.
  v2f cxA0 = v2f{__cosf(0.5f * xv0.x), __cosf(0.5f * xv1.x)};
  v2f sxA0 = v2f{__sinf(0.5f * xv0.x), __sinf(0.5f * xv1.x)};
  v2f cxA1 = v2f{__cosf(0.5f * xv0.y), __cosf(0.5f * xv1.y)};
  v2f sxA1 = v2f{__sinf(0.5f * xv0.y), __sinf(0.5f * xv1.y)};
  v2f cxA2 = v2f{__cosf(0.5f * xv0.z), __cosf(0.5f * xv1.z)};
  v2f sxA2 = v2f{__sinf(0.5f * xv0.z), __sinf(0.5f * xv1.z)};
  v2f cxA3 = v2f{__cosf(0.5f * xv0.w), __cosf(0.5f * xv1.w)};
  v2f sxA3 = v2f{__sinf(0.5f * xv0.w), __sinf(0.5f * xv1.w)};
  v2f cxB0 = v2f{__cosf(0.5f * xv2.x), __cosf(0.5f * xv3.x)};
  v2f sxB0 = v2f{__sinf(0.5f * xv2.x), __sinf(0.5f * xv3.x)};
  v2f cxB1 = v2f{__cosf(0.5f * xv2.y), __cosf(0.5f * xv3.y)};
  v2f sxB1 = v2f{__sinf(0.5f * xv2.y), __sinf(0.5f * xv3.y)};
  v2f cxB2 = v2f{__cosf(0.5f * xv2.z), __cosf(0.5f * xv3.z)};
  v2f sxB2 = v2f{__sinf(0.5f * xv2.z), __sinf(0.5f * xv3.z)};
  v2f cxB3 = v2f{__cosf(0.5f * xv2.w), __cosf(0.5f * xv3.w)};
  v2f sxB3 = v2f{__sinf(0.5f * xv2.w), __sinf(0.5f * xv3.w)};

  __syncthreads();  // Msh ready

  // ---- State: named v2f (SSA-direct, cannot be aggregate-demoted) ----
  v2f srA_0, srA_1, srA_2, srA_3, srA_4, srA_5, srA_6, srA_7;
  v2f srA_8, srA_9, srA_10, srA_11, srA_12, srA_13, srA_14, srA_15;
  v2f siA_0, siA_1, siA_2, siA_3, siA_4, siA_5, siA_6, siA_7;
  v2f siA_8, siA_9, siA_10, siA_11, siA_12, siA_13, siA_14, siA_15;
  v2f srB_0, srB_1, srB_2, srB_3, srB_4, srB_5, srB_6, srB_7;
  v2f srB_8, srB_9, srB_10, srB_11, srB_12, srB_13, srB_14, srB_15;
  v2f siB_0, siB_1, siB_2, siB_3, siB_4, siB_5, siB_6, siB_7;
  v2f siB_8, siB_9, siB_10, siB_11, siB_12, siB_13, siB_14, siB_15;
  v2f grA, giA, drA, diA, grB, giB, drB, diB;

  // ---- Layer 0 on |0000>: product state built in-place LSB-first ----
  MAKE_G2_AB(3, 3);
  srA_0 = grA;  siA_0 = giA;  srA_1 = -drA; siA_1 = diA;
  srB_0 = grB;  siB_0 = giB;  srB_1 = -drB; siB_1 = diB;
  MAKE_G2_AB(2, 2);
  L0_EXPAND(A, 1, 3); L0_EXPAND(A, 0, 2);
  L0_EXPAND(B, 1, 3); L0_EXPAND(B, 0, 2);
  MAKE_G2_AB(1, 1);
  L0_EXPAND(A, 3, 7); L0_EXPAND(A, 2, 6); L0_EXPAND(A, 1, 5); L0_EXPAND(A, 0, 4);
  L0_EXPAND(B, 3, 7); L0_EXPAND(B, 2, 6); L0_EXPAND(B, 1, 5); L0_EXPAND(B, 0, 4);
  MAKE_G2_AB(0, 0);
  L0_EXPAND(A, 7, 15); L0_EXPAND(A, 6, 14); L0_EXPAND(A, 5, 13); L0_EXPAND(A, 4, 12);
  L0_EXPAND(A, 3, 11); L0_EXPAND(A, 2, 10); L0_EXPAND(A, 1, 9);  L0_EXPAND(A, 0, 8);
  L0_EXPAND(B, 7, 15); L0_EXPAND(B, 6, 14); L0_EXPAND(B, 5, 13); L0_EXPAND(B, 4, 12);
  L0_EXPAND(B, 3, 11); L0_EXPAND(B, 2, 10); L0_EXPAND(B, 1, 9);  L0_EXPAND(B, 0, 8);
  CNOTS(A); CNOTS(B);

  // ---- Layers 1..2 (full complex gates) ----
#pragma unroll
  for (int l = 1; l < 3; ++l) {
    MAKE_G2_AB(l * 4 + 0, 0); SU2_W0(A); SU2_W0(B);
    MAKE_G2_AB(l * 4 + 1, 1); SU2_W1(A); SU2_W1(B);
    MAKE_G2_AB(l * 4 + 2, 2); SU2_W2(A); SU2_W2(B);
    MAKE_G2_AB(l * 4 + 3, 3); SU2_W3(A); SU2_W3(B);
    CNOTS(A); CNOTS(B);
  }

  // ---- Layer 3: M real (RZ folded out, exact) ----
  MAKE_G2_REAL_AB(12, 0); SU2_W0(A); SU2_W0(B);
  MAKE_G2_REAL_AB(13, 1); SU2_W1(A); SU2_W1(B);
  MAKE_G2_REAL_AB(14, 2); SU2_W2(A); SU2_W2(B);
  MAKE_G2_REAL_AB(15, 3); SU2_W3(A); SU2_W3(B);
  CNOTS(A); CNOTS(B);

  // ---- Measurement ----
  v2f o0A, o1A, o2A, o3A, o0B, o1B, o2B, o3B;
  MEASURE(A);
  MEASURE(B);

  float4* o4 = reinterpret_cast<float4*>(out);
  o4[4 * t + 0] = make_float4(o0A.x, o1A.x, o2A.x, o3A.x);
  o4[4 * t + 1] = make_float4(o0A.y, o1A.y, o2A.y, o3A.y);
  o4[4 * t + 2] = make_float4(o0B.x, o1B.x, o2B.x, o3B.x);
  o4[4 * t + 3] = make_float4(o0B.y, o1B.y, o2B.y, o3B.y);
}

extern "C" void kernel_launch(void* const* d_in, const int* in_sizes, int n_in,
                              void* d_out, int out_size, void* d_ws, size_t ws_size,
                              hipStream_t stream) {
  const float* x = (const float*)d_in[0];
  const float* w = (const float*)d_in[1];
  float* out = (float*)d_out;
  int nb = in_sizes[0] / 4;  // batch elements; B=524288
  int threads = nb / 4;      // 4 elements per thread -> 131072
  int blocks = threads / 256;  // exact: 512 blocks
  hipLaunchKernelGGL(qlayer_main, dim3(blocks), dim3(256), 0, stream, x, w, out);
}

// Round 8
// 74.771 us; speedup vs baseline: 2.1107x; 1.0454x over previous
//
#include <hip/hip_runtime.h>

// QuantumLayer: 4-qubit, 4-layer VQC over batch B.
// R14: R6's exact geometry (2 elems/thread, v2f, 1024 blocks) with state in
// NAMED v2f variables instead of v2f arrays.
//  Rationale: R8-R10 proved this compiler aggregate-demotes state ARRAYS to
//  scratch in this kernel shape (float arrays: VGPR 40/64, ~400MB spill
//  traffic). R6's v2f arrays were never counter-verified (kernel always
//  below the fill rows in top-5); its ~32us at ~38% est. VALU efficiency is
//  consistent with hidden spill. R13 proved named v2f codegen is clean but
//  confounded with 2x register pressure (2 streams). This build changes ONE
//  variable vs R6: arrays -> named vars. ~100 VGPR expected, no cap.
//  Kept: fused precompute (M=RZ*RY splatted v2f in LDS), layer-3 RZ dropped
//  (exact), full unroll (CNOTs = SSA renames), folded butterfly measurement.
// State indexing: flat k = w0*8 + w1*4 + w2*2 + w3  (wire i -> bit (3-i)).

typedef float v2f __attribute__((ext_vector_type(2)));

// ---- gate application on a named pair ----
#define GATE_APPLY(K0, K1) do {                                   \
    v2f a0r = sr_##K0, a0i = si_##K0;                             \
    v2f a1r = sr_##K1, a1i = si_##K1;                             \
    sr_##K0 = gr * a0r - gi * a0i + dr * a1r - di * a1i;          \
    si_##K0 = gr * a0i + gi * a0r + dr * a1i + di * a1r;          \
    sr_##K1 = gr * a1r + gi * a1i - dr * a0r - di * a0i;          \
    si_##K1 = gr * a1i - gi * a1r - dr * a0i + di * a0r;          \
  } while (0)

#define SU2_W0 do { GATE_APPLY(0,8);  GATE_APPLY(1,9);   GATE_APPLY(2,10);  GATE_APPLY(3,11); \
                    GATE_APPLY(4,12); GATE_APPLY(5,13);  GATE_APPLY(6,14);  GATE_APPLY(7,15); } while (0)
#define SU2_W1 do { GATE_APPLY(0,4);  GATE_APPLY(1,5);   GATE_APPLY(2,6);   GATE_APPLY(3,7);  \
                    GATE_APPLY(8,12); GATE_APPLY(9,13);  GATE_APPLY(10,14); GATE_APPLY(11,15); } while (0)
#define SU2_W2 do { GATE_APPLY(0,2);  GATE_APPLY(1,3);   GATE_APPLY(4,6);   GATE_APPLY(5,7);  \
                    GATE_APPLY(8,10); GATE_APPLY(9,11);  GATE_APPLY(12,14); GATE_APPLY(13,15); } while (0)
#define SU2_W3 do { GATE_APPLY(0,1);  GATE_APPLY(2,3);   GATE_APPLY(4,5);   GATE_APPLY(6,7);  \
                    GATE_APPLY(8,9);  GATE_APPLY(10,11); GATE_APPLY(12,13); GATE_APPLY(14,15); } while (0)

// CNOT block (2,3)(1,2)(0,1)(3,0): pure SSA renames.
#define SWAPK(A, B) do { v2f t_r = sr_##A; sr_##A = sr_##B; sr_##B = t_r; \
                         v2f t_i = si_##A; si_##A = si_##B; si_##B = t_i; } while (0)
#define CNOTS do { SWAPK(2,3);  SWAPK(6,7);  SWAPK(10,11); SWAPK(14,15); \
                   SWAPK(4,6);  SWAPK(5,7);  SWAPK(12,14); SWAPK(13,15); \
                   SWAPK(8,12); SWAPK(9,13); SWAPK(10,14); SWAPK(11,15); \
                   SWAPK(1,9);  SWAPK(3,11); SWAPK(5,13);  SWAPK(7,15); } while (0)

// Layer-0 product-state expansion: K keeps new-bit=0 (* g), KP gets
// new-bit=1 (* -conj(d) = (-dr, +di)).
#define L0_EXPAND(K, KP) do {                   \
    v2f e_ar = sr_##K, e_ai = si_##K;           \
    sr_##KP = -(dr * e_ar) - di * e_ai;         \
    si_##KP = di * e_ar - dr * e_ai;            \
    sr_##K  = gr * e_ar - gi * e_ai;            \
    si_##K  = gr * e_ai + gi * e_ar;            \
  } while (0)

// G = M * RX(c,s) is SU(2): G = [[g, d], [-conj(d), conj(g)]].
#define MAKE_G2(IDX, Q) do {                                      \
    v2f m_ar = Msh[(IDX) * 4 + 0], m_ai = Msh[(IDX) * 4 + 1];     \
    v2f m_br = Msh[(IDX) * 4 + 2], m_bi = Msh[(IDX) * 4 + 3];     \
    gr = m_ar * cx##Q + m_bi * sx##Q;                             \
    gi = m_ai * cx##Q - m_br * sx##Q;                             \
    dr = m_ai * sx##Q + m_br * cx##Q;                             \
    di = m_bi * cx##Q - m_ar * sx##Q;                             \
  } while (0)

// Layer-3 variant: RZ == I there, so M real (ai = bi = 0).
#define MAKE_G2_REAL(IDX, Q) do {                                 \
    v2f m_ar = Msh[(IDX) * 4 + 0], m_br = Msh[(IDX) * 4 + 2];     \
    gr = m_ar * cx##Q;  gi = -(m_br * sx##Q);                     \
    dr = m_br * cx##Q;  di = -(m_ar * sx##Q);                     \
  } while (0)

#define PSQ(K) (sr_##K * sr_##K + si_##K * si_##K)

__global__ __launch_bounds__(256) void qlayer_main(const float* __restrict__ x,
                                                   const float* __restrict__ w,
                                                   float* __restrict__ out) {
  // ---- Fused precompute: M = RZ(pz)*RY(py) per (layer, wire); layer 3 uses
  // RZ = I (exact). Splatted v2f quads {ar,ai,br,bi} in LDS (512 B). ----
  __shared__ v2f Msh[16 * 4];
  int tid = threadIdx.x;
  if (tid < 16) {
    int l = tid >> 2, q = tid & 3;
    float ay = 0.5f * w[8 * l + q];
    float az = (l == 3) ? 0.0f : 0.5f * w[8 * l + 4 + q];
    float cy = __cosf(ay), sy = __sinf(ay);
    float cz = __cosf(az), sz = __sinf(az);
    float ar = cz * cy, ai = -sz * cy, br = -cz * sy, bi = sz * sy;
    Msh[tid * 4 + 0] = v2f{ar, ar};
    Msh[tid * 4 + 1] = v2f{ai, ai};
    Msh[tid * 4 + 2] = v2f{br, br};
    Msh[tid * 4 + 3] = v2f{bi, bi};
  }

  int t = blockIdx.x * blockDim.x + tid;  // owns batch elems 2t, 2t+1
  const float4* x4 = reinterpret_cast<const float4*>(x);
  float4 xv0 = x4[2 * t + 0], xv1 = x4[2 * t + 1];

  v2f cx0 = v2f{__cosf(0.5f * xv0.x), __cosf(0.5f * xv1.x)};
  v2f sx0 = v2f{__sinf(0.5f * xv0.x), __sinf(0.5f * xv1.x)};
  v2f cx1 = v2f{__cosf(0.5f * xv0.y), __cosf(0.5f * xv1.y)};
  v2f sx1 = v2f{__sinf(0.5f * xv0.y), __sinf(0.5f * xv1.y)};
  v2f cx2 = v2f{__cosf(0.5f * xv0.z), __cosf(0.5f * xv1.z)};
  v2f sx2 = v2f{__sinf(0.5f * xv0.z), __sinf(0.5f * xv1.z)};
  v2f cx3 = v2f{__cosf(0.5f * xv0.w), __cosf(0.5f * xv1.w)};
  v2f sx3 = v2f{__sinf(0.5f * xv0.w), __sinf(0.5f * xv1.w)};

  __syncthreads();  // Msh ready

  // ---- State: named v2f (SSA-direct; aggregate demotion impossible) ----
  v2f sr_0, sr_1, sr_2, sr_3, sr_4, sr_5, sr_6, sr_7;
  v2f sr_8, sr_9, sr_10, sr_11, sr_12, sr_13, sr_14, sr_15;
  v2f si_0, si_1, si_2, si_3, si_4, si_5, si_6, si_7;
  v2f si_8, si_9, si_10, si_11, si_12, si_13, si_14, si_15;
  v2f gr, gi, dr, di;

  // ---- Layer 0 on |0000>: product state built in-place LSB-first ----
  MAKE_G2(3, 3);
  sr_0 = gr;  si_0 = gi;  sr_1 = -dr; si_1 = di;
  MAKE_G2(2, 2);
  L0_EXPAND(1, 3); L0_EXPAND(0, 2);
  MAKE_G2(1, 1);
  L0_EXPAND(3, 7); L0_EXPAND(2, 6); L0_EXPAND(1, 5); L0_EXPAND(0, 4);
  MAKE_G2(0, 0);
  L0_EXPAND(7, 15); L0_EXPAND(6, 14); L0_EXPAND(5, 13); L0_EXPAND(4, 12);
  L0_EXPAND(3, 11); L0_EXPAND(2, 10); L0_EXPAND(1, 9);  L0_EXPAND(0, 8);
  CNOTS;

  // ---- Layers 1..2 (full complex gates) ----
#pragma unroll
  for (int l = 1; l < 3; ++l) {
    MAKE_G2(l * 4 + 0, 0); SU2_W0;
    MAKE_G2(l * 4 + 1, 1); SU2_W1;
    MAKE_G2(l * 4 + 2, 2); SU2_W2;
    MAKE_G2(l * 4 + 3, 3); SU2_W3;
    CNOTS;
  }

  // ---- Layer 3: M real (RZ folded out, exact) ----
  MAKE_G2_REAL(12, 0); SU2_W0;
  MAKE_G2_REAL(13, 1); SU2_W1;
  MAKE_G2_REAL(14, 2); SU2_W2;
  MAKE_G2_REAL(15, 3); SU2_W3;
  CNOTS;

  // ---- Measurement: butterfly over p_k = |amp_k|^2;
  // o_j = sum_k p_k * (bit(3-j)? -1 : +1). ----
  v2f p0 = PSQ(0),  p1 = PSQ(1),  p2 = PSQ(2),  p3 = PSQ(3);
  v2f p4 = PSQ(4),  p5 = PSQ(5),  p6 = PSQ(6),  p7 = PSQ(7);
  v2f p8 = PSQ(8),  p9 = PSQ(9),  pa = PSQ(10), pb = PSQ(11);
  v2f pc = PSQ(12), pd = PSQ(13), pe = PSQ(14), pf = PSQ(15);

  v2f s20 = p0 + p1, d20 = p0 - p1,  s21 = p2 + p3, d21 = p2 - p3;
  v2f s22 = p4 + p5, d22 = p4 - p5,  s23 = p6 + p7, d23 = p6 - p7;
  v2f s24 = p8 + p9, d24 = p8 - p9,  s25 = pa + pb, d25 = pa - pb;
  v2f s26 = pc + pd, d26 = pc - pd,  s27 = pe + pf, d27 = pe - pf;
  v2f o3 = ((d20 + d21) + (d22 + d23)) + ((d24 + d25) + (d26 + d27));

  v2f s40 = s20 + s21, d40 = s20 - s21, s41 = s22 + s23, d41 = s22 - s23;
  v2f s42 = s24 + s25, d42 = s24 - s25, s43 = s26 + s27, d43 = s26 - s27;
  v2f o2 = (d40 + d41) + (d42 + d43);

  v2f s8a = s40 + s41, s8b = s42 + s43;
  v2f d8a = s40 - s41, d8b = s42 - s43;
  v2f o1 = d8a + d8b;
  v2f o0 = s8a - s8b;

  float4* o4 = reinterpret_cast<float4*>(out);
  o4[2 * t + 0] = make_float4(o0.x, o1.x, o2.x, o3.x);
  o4[2 * t + 1] = make_float4(o0.y, o1.y, o2.y, o3.y);
}

extern "C" void kernel_launch(void* const* d_in, const int* in_sizes, int n_in,
                              void* d_out, int out_size, void* d_ws, size_t ws_size,
                              hipStream_t stream) {
  const float* x = (const float*)d_in[0];
  const float* w = (const float*)d_in[1];
  float* out = (float*)d_out;
  int nb = in_sizes[0] / 4;   // batch elements; B=524288
  int threads = nb / 2;       // 2 elements per thread -> 262144
  int blocks = threads / 256; // exact: 1024 blocks
  hipLaunchKernelGGL(qlayer_main, dim3(blocks), dim3(256), 0, stream, x, w, out);
}

// Round 9
// 74.484 us; speedup vs baseline: 2.1188x; 1.0039x over previous
//
#include <hip/hip_runtime.h>

// QuantumLayer: 4-qubit, 4-layer VQC over batch B.
// R15 = R14 (named v2f, 2 elems/thread, 1024 blocks — best @74.77us) with ONE
// change: LDS gate-coefficient access restructured from 16 interleaved
// load-points (4 ds_read_b64 + immediate dependent use, x16 gates) to ONE
// batched 16-load point per layer, PREFETCHED one layer ahead so the current
// layer's ~512-FMA apply block hides the latency.
//  Mechanism under test: all waves run identical straight-line code in near-
//  lockstep -> every wave stalls on the same lgkmcnt site simultaneously
//  (LDS latency ~120cyc, m117), so TLP can't cover it; explains flat
//  occupancy curve (2/3/4/8 waves ~equal) and ILP nulls.
//  Cost: +32 VGPR coefficient locals -> ~155 peak, 3 waves/SIMD (R6 proved
//  3 waves == 4 waves for this kernel).
//  Kept: fused precompute (M=RZ*RY splatted v2f in LDS), layer-3 RZ dropped
//  (exact), full unroll (CNOTs = SSA renames), folded butterfly measurement.
// State indexing: flat k = w0*8 + w1*4 + w2*2 + w3  (wire i -> bit (3-i)).

typedef float v2f __attribute__((ext_vector_type(2)));

// ---- batched load of layer L's 4 gates' splatted coeffs (16 ds_read_b64) ----
#define LOAD_LAYER(L) do {                                        \
    c_ar0 = Msh[((L) * 4 + 0) * 4 + 0]; c_ai0 = Msh[((L) * 4 + 0) * 4 + 1]; \
    c_br0 = Msh[((L) * 4 + 0) * 4 + 2]; c_bi0 = Msh[((L) * 4 + 0) * 4 + 3]; \
    c_ar1 = Msh[((L) * 4 + 1) * 4 + 0]; c_ai1 = Msh[((L) * 4 + 1) * 4 + 1]; \
    c_br1 = Msh[((L) * 4 + 1) * 4 + 2]; c_bi1 = Msh[((L) * 4 + 1) * 4 + 3]; \
    c_ar2 = Msh[((L) * 4 + 2) * 4 + 0]; c_ai2 = Msh[((L) * 4 + 2) * 4 + 1]; \
    c_br2 = Msh[((L) * 4 + 2) * 4 + 2]; c_bi2 = Msh[((L) * 4 + 2) * 4 + 3]; \
    c_ar3 = Msh[((L) * 4 + 3) * 4 + 0]; c_ai3 = Msh[((L) * 4 + 3) * 4 + 1]; \
    c_br3 = Msh[((L) * 4 + 3) * 4 + 2]; c_bi3 = Msh[((L) * 4 + 3) * 4 + 3]; \
  } while (0)

// G = M * RX(c,s) is SU(2): G = [[g, d], [-conj(d), conj(g)]].
#define MAKE_G2_Q(Q) do {                                         \
    gr##Q = c_ar##Q * cx##Q + c_bi##Q * sx##Q;                    \
    gi##Q = c_ai##Q * cx##Q - c_br##Q * sx##Q;                    \
    dr##Q = c_ai##Q * sx##Q + c_br##Q * cx##Q;                    \
    di##Q = c_bi##Q * cx##Q - c_ar##Q * sx##Q;                    \
  } while (0)

// Layer-3 variant: RZ == I there, so M real (ai = bi = 0).
#define MAKE_G2_REAL_Q(Q) do {                                    \
    gr##Q = c_ar##Q * cx##Q;  gi##Q = -(c_br##Q * sx##Q);         \
    dr##Q = c_br##Q * cx##Q;  di##Q = -(c_ar##Q * sx##Q);         \
  } while (0)

// ---- gate application (gate suffix G) on a named pair ----
#define GATE_APPLY(G, K0, K1) do {                                        \
    v2f a0r = sr_##K0, a0i = si_##K0;                                     \
    v2f a1r = sr_##K1, a1i = si_##K1;                                     \
    sr_##K0 = gr##G * a0r - gi##G * a0i + dr##G * a1r - di##G * a1i;      \
    si_##K0 = gr##G * a0i + gi##G * a0r + dr##G * a1i + di##G * a1r;      \
    sr_##K1 = gr##G * a1r + gi##G * a1i - dr##G * a0r - di##G * a0i;      \
    si_##K1 = gr##G * a1i - gi##G * a1r - dr##G * a0i + di##G * a0r;      \
  } while (0)

#define SU2_W0(G) do { GATE_APPLY(G,0,8);  GATE_APPLY(G,1,9);   GATE_APPLY(G,2,10);  GATE_APPLY(G,3,11); \
                       GATE_APPLY(G,4,12); GATE_APPLY(G,5,13);  GATE_APPLY(G,6,14);  GATE_APPLY(G,7,15); } while (0)
#define SU2_W1(G) do { GATE_APPLY(G,0,4);  GATE_APPLY(G,1,5);   GATE_APPLY(G,2,6);   GATE_APPLY(G,3,7);  \
                       GATE_APPLY(G,8,12); GATE_APPLY(G,9,13);  GATE_APPLY(G,10,14); GATE_APPLY(G,11,15); } while (0)
#define SU2_W2(G) do { GATE_APPLY(G,0,2);  GATE_APPLY(G,1,3);   GATE_APPLY(G,4,6);   GATE_APPLY(G,5,7);  \
                       GATE_APPLY(G,8,10); GATE_APPLY(G,9,11);  GATE_APPLY(G,12,14); GATE_APPLY(G,13,15); } while (0)
#define SU2_W3(G) do { GATE_APPLY(G,0,1);  GATE_APPLY(G,2,3);   GATE_APPLY(G,4,5);   GATE_APPLY(G,6,7);  \
                       GATE_APPLY(G,8,9);  GATE_APPLY(G,10,11); GATE_APPLY(G,12,13); GATE_APPLY(G,14,15); } while (0)

// CNOT block (2,3)(1,2)(0,1)(3,0): pure SSA renames.
#define SWAPK(A, B) do { v2f t_r = sr_##A; sr_##A = sr_##B; sr_##B = t_r; \
                         v2f t_i = si_##A; si_##A = si_##B; si_##B = t_i; } while (0)
#define CNOTS do { SWAPK(2,3);  SWAPK(6,7);  SWAPK(10,11); SWAPK(14,15); \
                   SWAPK(4,6);  SWAPK(5,7);  SWAPK(12,14); SWAPK(13,15); \
                   SWAPK(8,12); SWAPK(9,13); SWAPK(10,14); SWAPK(11,15); \
                   SWAPK(1,9);  SWAPK(3,11); SWAPK(5,13);  SWAPK(7,15); } while (0)

// Layer-0 product-state expansion with gate suffix G: K keeps new-bit=0
// (* g), KP gets new-bit=1 (* -conj(d) = (-dr, +di)).
#define L0_EXPAND(G, K, KP) do {                        \
    v2f e_ar = sr_##K, e_ai = si_##K;                   \
    sr_##KP = -(dr##G * e_ar) - di##G * e_ai;           \
    si_##KP = di##G * e_ar - dr##G * e_ai;              \
    sr_##K  = gr##G * e_ar - gi##G * e_ai;              \
    si_##K  = gr##G * e_ai + gi##G * e_ar;              \
  } while (0)

#define PSQ(K) (sr_##K * sr_##K + si_##K * si_##K)

__global__ __launch_bounds__(256) void qlayer_main(const float* __restrict__ x,
                                                   const float* __restrict__ w,
                                                   float* __restrict__ out) {
  // ---- Fused precompute: M = RZ(pz)*RY(py) per (layer, wire); layer 3 uses
  // RZ = I (exact). Splatted v2f quads {ar,ai,br,bi} in LDS (512 B). ----
  __shared__ v2f Msh[16 * 4];
  int tid = threadIdx.x;
  if (tid < 16) {
    int l = tid >> 2, q = tid & 3;
    float ay = 0.5f * w[8 * l + q];
    float az = (l == 3) ? 0.0f : 0.5f * w[8 * l + 4 + q];
    float cy = __cosf(ay), sy = __sinf(ay);
    float cz = __cosf(az), sz = __sinf(az);
    float ar = cz * cy, ai = -sz * cy, br = -cz * sy, bi = sz * sy;
    Msh[tid * 4 + 0] = v2f{ar, ar};
    Msh[tid * 4 + 1] = v2f{ai, ai};
    Msh[tid * 4 + 2] = v2f{br, br};
    Msh[tid * 4 + 3] = v2f{bi, bi};
  }

  int t = blockIdx.x * blockDim.x + tid;  // owns batch elems 2t, 2t+1
  const float4* x4 = reinterpret_cast<const float4*>(x);
  float4 xv0 = x4[2 * t + 0], xv1 = x4[2 * t + 1];

  v2f cx0 = v2f{__cosf(0.5f * xv0.x), __cosf(0.5f * xv1.x)};
  v2f sx0 = v2f{__sinf(0.5f * xv0.x), __sinf(0.5f * xv1.x)};
  v2f cx1 = v2f{__cosf(0.5f * xv0.y), __cosf(0.5f * xv1.y)};
  v2f sx1 = v2f{__sinf(0.5f * xv0.y), __sinf(0.5f * xv1.y)};
  v2f cx2 = v2f{__cosf(0.5f * xv0.z), __cosf(0.5f * xv1.z)};
  v2f sx2 = v2f{__sinf(0.5f * xv0.z), __sinf(0.5f * xv1.z)};
  v2f cx3 = v2f{__cosf(0.5f * xv0.w), __cosf(0.5f * xv1.w)};
  v2f sx3 = v2f{__sinf(0.5f * xv0.w), __sinf(0.5f * xv1.w)};

  __syncthreads();  // Msh ready

  // ---- State + gate + coefficient locals: all NAMED (SSA-direct) ----
  v2f sr_0, sr_1, sr_2, sr_3, sr_4, sr_5, sr_6, sr_7;
  v2f sr_8, sr_9, sr_10, sr_11, sr_12, sr_13, sr_14, sr_15;
  v2f si_0, si_1, si_2, si_3, si_4, si_5, si_6, si_7;
  v2f si_8, si_9, si_10, si_11, si_12, si_13, si_14, si_15;
  v2f c_ar0, c_ai0, c_br0, c_bi0, c_ar1, c_ai1, c_br1, c_bi1;
  v2f c_ar2, c_ai2, c_br2, c_bi2, c_ar3, c_ai3, c_br3, c_bi3;
  v2f gr0, gi0, dr0, di0, gr1, gi1, dr1, di1;
  v2f gr2, gi2, dr2, di2, gr3, gi3, dr3, di3;

  // ---- Layer 0 on |0000>: build all 4 gates, prefetch layer 1, then the
  // product-state expansion (114 FMA-ops) hides the prefetch latency. ----
  LOAD_LAYER(0);
  MAKE_G2_Q(3); MAKE_G2_Q(2); MAKE_G2_Q(1); MAKE_G2_Q(0);
  LOAD_LAYER(1);  // prefetch: c_* dead until next layer's builds
  sr_0 = gr3;  si_0 = gi3;  sr_1 = -dr3; si_1 = di3;
  L0_EXPAND(2, 1, 3); L0_EXPAND(2, 0, 2);
  L0_EXPAND(1, 3, 7); L0_EXPAND(1, 2, 6); L0_EXPAND(1, 1, 5); L0_EXPAND(1, 0, 4);
  L0_EXPAND(0, 7, 15); L0_EXPAND(0, 6, 14); L0_EXPAND(0, 5, 13); L0_EXPAND(0, 4, 12);
  L0_EXPAND(0, 3, 11); L0_EXPAND(0, 2, 10); L0_EXPAND(0, 1, 9);  L0_EXPAND(0, 0, 8);
  CNOTS;

  // ---- Layers 1..2: build 4 gates, prefetch next layer, apply (512 FMAs
  // hide the 16 ds_read_b64), CNOT renames. ----
#pragma unroll
  for (int l = 1; l < 3; ++l) {
    MAKE_G2_Q(0); MAKE_G2_Q(1); MAKE_G2_Q(2); MAKE_G2_Q(3);
    LOAD_LAYER(l + 1);
    SU2_W0(0); SU2_W1(1); SU2_W2(2); SU2_W3(3);
    CNOTS;
  }

  // ---- Layer 3: M real (RZ folded out, exact); coeffs already prefetched ----
  MAKE_G2_REAL_Q(0); MAKE_G2_REAL_Q(1); MAKE_G2_REAL_Q(2); MAKE_G2_REAL_Q(3);
  SU2_W0(0); SU2_W1(1); SU2_W2(2); SU2_W3(3);
  CNOTS;

  // ---- Measurement: butterfly over p_k = |amp_k|^2;
  // o_j = sum_k p_k * (bit(3-j)? -1 : +1). ----
  v2f p0 = PSQ(0),  p1 = PSQ(1),  p2 = PSQ(2),  p3 = PSQ(3);
  v2f p4 = PSQ(4),  p5 = PSQ(5),  p6 = PSQ(6),  p7 = PSQ(7);
  v2f p8 = PSQ(8),  p9 = PSQ(9),  pa = PSQ(10), pb = PSQ(11);
  v2f pc = PSQ(12), pd = PSQ(13), pe = PSQ(14), pf = PSQ(15);

  v2f s20 = p0 + p1, d20 = p0 - p1,  s21 = p2 + p3, d21 = p2 - p3;
  v2f s22 = p4 + p5, d22 = p4 - p5,  s23 = p6 + p7, d23 = p6 - p7;
  v2f s24 = p8 + p9, d24 = p8 - p9,  s25 = pa + pb, d25 = pa - pb;
  v2f s26 = pc + pd, d26 = pc - pd,  s27 = pe + pf, d27 = pe - pf;
  v2f o3 = ((d20 + d21) + (d22 + d23)) + ((d24 + d25) + (d26 + d27));

  v2f s40 = s20 + s21, d40 = s20 - s21, s41 = s22 + s23, d41 = s22 - s23;
  v2f s42 = s24 + s25, d42 = s24 - s25, s43 = s26 + s27, d43 = s26 - s27;
  v2f o2 = (d40 + d41) + (d42 + d43);

  v2f s8a = s40 + s41, s8b = s42 + s43;
  v2f d8a = s40 - s41, d8b = s42 - s43;
  v2f o1 = d8a + d8b;
  v2f o0 = s8a - s8b;

  float4* o4 = reinterpret_cast<float4*>(out);
  o4[2 * t + 0] = make_float4(o0.x, o1.x, o2.x, o3.x);
  o4[2 * t + 1] = make_float4(o0.y, o1.y, o2.y, o3.y);
}

extern "C" void kernel_launch(void* const* d_in, const int* in_sizes, int n_in,
                              void* d_out, int out_size, void* d_ws, size_t ws_size,
                              hipStream_t stream) {
  const float* x = (const float*)d_in[0];
  const float* w = (const float*)d_in[1];
  float* out = (float*)d_out;
  int nb = in_sizes[0] / 4;   // batch elements; B=524288
  int threads = nb / 2;       // 2 elements per thread -> 262144
  int blocks = threads / 256; // exact: 1024 blocks
  hipLaunchKernelGGL(qlayer_main, dim3(blocks), dim3(256), 0, stream, x, w, out);
}